// Round 3
// baseline (1446.014 us; speedup 1.0000x reference)
//
#include <hip/hip_runtime.h>

// ---------------------------------------------------------------------------
// Swin block (BS=4, GRID=64, D=1024, WS=8, NH=16) on MI355X.
// bf16 MFMA GEMMs (fp32 accumulate), fp32 residual/LN/softmax.
// m97-structure GEMM (128x128, BK=32, global_load_lds w16, XOR-swizzle, XCD
// swizzle). Round 3: ws-size-adaptive buffer plan (suspected ws overflow
// caused round-2 GPU memory fault); fp32 residual stream lives in d_out.
// ---------------------------------------------------------------------------

typedef __bf16 bf16x8 __attribute__((ext_vector_type(8)));
typedef float f32x4 __attribute__((ext_vector_type(4)));

__device__ __forceinline__ unsigned short f2b(float x) {
  union { float f; unsigned u; } c; c.f = x;
  unsigned r = c.u + 0x7fffu + ((c.u >> 16) & 1u);   // RNE
  return (unsigned short)(r >> 16);
}

__device__ __forceinline__ void gload16(const void* gp, void* lp) {
  __builtin_amdgcn_global_load_lds(
      (const __attribute__((address_space(1))) void*)gp,
      (__attribute__((address_space(3))) void*)lp, 16, 0, 0);
}

// ---------------------------------------------------------------------------
// Weight convert: fp32 [K][N] -> bf16 [N][K]  (transpose + cast), 32x32 tiles.
// ---------------------------------------------------------------------------
__global__ void wconv(const float* __restrict__ src, unsigned short* __restrict__ dst,
                      int K, int N) {
  __shared__ float t[32][33];
  const int tx = threadIdx.x, ty = threadIdx.y;
  const int n0 = blockIdx.x * 32, k0 = blockIdx.y * 32;
#pragma unroll
  for (int i = 0; i < 4; ++i)
    t[ty + i * 8][tx] = src[(size_t)(k0 + ty + i * 8) * N + n0 + tx];
  __syncthreads();
#pragma unroll
  for (int i = 0; i < 4; ++i)
    dst[(size_t)(n0 + ty + i * 8) * K + k0 + tx] = f2b(t[tx][ty + i * 8]);
}

// ---------------------------------------------------------------------------
// LayerNorm over D=1024; optional fp32 copy + bf16 copy (GEMM A input).
// ---------------------------------------------------------------------------
__global__ __launch_bounds__(256) void ln_fused(
    const float* __restrict__ in, const float* __restrict__ gw,
    const float* __restrict__ bw, float* __restrict__ outf,
    unsigned short* __restrict__ outb) {
  const int row = blockIdx.x;
  const int t = threadIdx.x;
  const int w = t >> 6, l = t & 63;
  const float4 v = ((const float4*)(in + (size_t)row * 1024))[t];
  float s1 = v.x + v.y + v.z + v.w;
  float s2 = v.x * v.x + v.y * v.y + v.z * v.z + v.w * v.w;
#pragma unroll
  for (int d = 32; d >= 1; d >>= 1) { s1 += __shfl_down(s1, d); s2 += __shfl_down(s2, d); }
  __shared__ float red[8];
  if (l == 0) { red[w] = s1; red[4 + w] = s2; }
  __syncthreads();
  const float S1 = red[0] + red[1] + red[2] + red[3];
  const float S2 = red[4] + red[5] + red[6] + red[7];
  const float mu = S1 * (1.0f / 1024.0f);
  const float rsg = rsqrtf(S2 * (1.0f / 1024.0f) - mu * mu + 1e-5f);
  const float4 g4 = ((const float4*)gw)[t];
  const float4 b4 = ((const float4*)bw)[t];
  float4 y;
  y.x = (v.x - mu) * rsg * g4.x + b4.x;
  y.y = (v.y - mu) * rsg * g4.y + b4.y;
  y.z = (v.z - mu) * rsg * g4.z + b4.z;
  y.w = (v.w - mu) * rsg * g4.w + b4.w;
  if (outf) ((float4*)(outf + (size_t)row * 1024))[t] = y;
  ushort4 ob;
  ob.x = f2b(y.x); ob.y = f2b(y.y); ob.z = f2b(y.z); ob.w = f2b(y.w);
  ((ushort4*)(outb + (size_t)row * 1024))[t] = ob;
}

// ---------------------------------------------------------------------------
// bf16 GEMM, C = A[M,K] @ B(BT[N,K]). 128x128 tile, BK=32, 4 waves,
// global_load_lds w16, XOR swizzle both sides, XCD swizzle (grid %8==0).
// EPI 0: bf16 out (+bias). EPI 1: fp32 out (+bias +residual).
// ---------------------------------------------------------------------------
template <int EPI>
__global__ __launch_bounds__(256, 3) void gemm_bt(
    const unsigned short* __restrict__ A, const unsigned short* __restrict__ BT,
    const float* __restrict__ bias, const float* __restrict__ res,
    void* __restrict__ Cout, int M, int N, int K) {
  __shared__ __align__(16) char lds[16384];
  char* ldsA = lds;
  char* ldsB = lds + 8192;
  const int tid = threadIdx.x;
  const int w = tid >> 6, l = tid & 63;
  const int lhi = l >> 4, llo = l & 15;
  const int cpx = gridDim.x >> 3;
  const int bid = (blockIdx.x & 7) * cpx + (blockIdx.x >> 3);
  const int tiles_n = N >> 7;
  const int tm = bid / tiles_n;
  const int tn = bid - tm * tiles_n;
  const int wr = w >> 1, wc = w & 1;

  size_t aoff[2], boff[2];
  int ldst[2];
#pragma unroll
  for (int p = 0; p < 2; ++p) {
    const int g = tid + p * 256;
    const int row = g >> 2;
    const int sl = (g & 3) ^ ((row >> 1) & 3);   // pre-swizzled source slot
    aoff[p] = (size_t)(tm * 128 + row) * K + sl * 8;
    boff[p] = (size_t)(tn * 128 + row) * K + sl * 8;
    ldst[p] = p * 4096 + w * 1024;               // wave-uniform LDS base
  }

  f32x4 acc[4][4] = {};
  for (int k0 = 0; k0 < K; k0 += 32) {
    gload16(A + aoff[0] + k0, ldsA + ldst[0]);
    gload16(A + aoff[1] + k0, ldsA + ldst[1]);
    gload16(BT + boff[0] + k0, ldsB + ldst[0]);
    gload16(BT + boff[1] + k0, ldsB + ldst[1]);
    __syncthreads();
    bf16x8 af[4], bg[4];
#pragma unroll
    for (int m = 0; m < 4; ++m) {
      const int row = wr * 64 + m * 16 + llo;
      const int sl = lhi ^ ((row >> 1) & 3);
      af[m] = *(const bf16x8*)(ldsA + row * 64 + sl * 16);
    }
#pragma unroll
    for (int n = 0; n < 4; ++n) {
      const int row = wc * 64 + n * 16 + llo;
      const int sl = lhi ^ ((row >> 1) & 3);
      bg[n] = *(const bf16x8*)(ldsB + row * 64 + sl * 16);
    }
#pragma unroll
    for (int m = 0; m < 4; ++m)
#pragma unroll
      for (int n = 0; n < 4; ++n)
        acc[m][n] = __builtin_amdgcn_mfma_f32_16x16x32_bf16(af[m], bg[n], acc[m][n], 0, 0, 0);
    __syncthreads();
  }

  const int row0 = tm * 128 + wr * 64 + lhi * 4;   // C/D: col=lane&15, row=(lane>>4)*4+j
  const int col0 = tn * 128 + wc * 64 + llo;
#pragma unroll
  for (int m = 0; m < 4; ++m)
#pragma unroll
    for (int j = 0; j < 4; ++j) {
      const int rowg = row0 + m * 16 + j;
#pragma unroll
      for (int n = 0; n < 4; ++n) {
        const int colg = col0 + n * 16;
        float v = acc[m][n][j] + bias[colg];
        if (EPI == 1) {
          v += res[(size_t)rowg * N + colg];
          ((float*)Cout)[(size_t)rowg * N + colg] = v;
        } else {
          ((unsigned short*)Cout)[(size_t)rowg * N + colg] = f2b(v);
        }
      }
    }
}

// ---------------------------------------------------------------------------
// Windowed MHSA: one wave per (window, head); 4 heads/block. Pointers are
// chunk-local (NB batches contiguous). MASKED=1: roll via (y+4)&63 on
// load/store, mask groups from ROLLED coords (56/60 boundaries).
// ---------------------------------------------------------------------------
template <int MASKED>
__global__ __launch_bounds__(256, 2) void attn_win(
    const unsigned short* __restrict__ qkv, unsigned short* __restrict__ out) {
  __shared__ __align__(16) char lds[65536];
  const int tid = threadIdx.x;
  const int w = tid >> 6, l = tid & 63;
  const int lhi = l >> 4, llo = l & 15;
  const int head = ((blockIdx.x & 3) << 2) | w;
  const int widx = blockIdx.x >> 2;
  const int batch = widx >> 6;                    // chunk-local batch
  const int wy = (widx >> 3) & 7, wx = widx & 7;
  char* Qb = lds + w * 16384;   // Q, later V^T
  char* Kb = Qb + 8192;         // K, later P
  const int lr = l >> 3, lc = l & 7;

  uint4 vv[8];
#pragma unroll
  for (int it = 0; it < 8; ++it) {
    const int r = it * 8 + lr;
    int y = wy * 8 + (r >> 3), x = wx * 8 + (r & 7);
    if (MASKED) { y = (y + 4) & 63; x = (x + 4) & 63; }
    const size_t base = ((size_t)batch * 4096 + y * 64 + x) * 3072 + head * 64 + lc * 8;
    const uint4 qv = *(const uint4*)(qkv + base);
    const uint4 kv = *(const uint4*)(qkv + base + 1024);
    vv[it] = *(const uint4*)(qkv + base + 2048);
    const int sl = lc ^ (r & 7);
    *(uint4*)(Qb + r * 128 + sl * 16) = qv;
    *(uint4*)(Kb + r * 128 + sl * 16) = kv;
  }

  f32x4 s[4][4] = {};
#pragma unroll
  for (int ks = 0; ks < 2; ++ks) {
    bf16x8 aq[4], bk[4];
#pragma unroll
    for (int m = 0; m < 4; ++m) {
      const int r = m * 16 + llo;
      const int sl = (ks * 4 + lhi) ^ (r & 7);
      aq[m] = *(const bf16x8*)(Qb + r * 128 + sl * 16);
    }
#pragma unroll
    for (int n = 0; n < 4; ++n) {
      const int r = n * 16 + llo;
      const int sl = (ks * 4 + lhi) ^ (r & 7);
      bk[n] = *(const bf16x8*)(Kb + r * 128 + sl * 16);
    }
#pragma unroll
    for (int m = 0; m < 4; ++m)
#pragma unroll
      for (int n = 0; n < 4; ++n)
        s[m][n] = __builtin_amdgcn_mfma_f32_16x16x32_bf16(aq[m], bk[n], s[m][n], 0, 0, 0);
  }

  int kg[4] = {0, 0, 0, 0};
  if (MASKED) {
#pragma unroll
    for (int n = 0; n < 4; ++n) {
      const int p = n * 16 + llo;
      const int y = wy * 8 + (p >> 3), x = wx * 8 + (p & 7);
      kg[n] = ((y < 56) ? 0 : ((y < 60) ? 1 : 2)) * 3 + ((x < 56) ? 0 : ((x < 60) ? 1 : 2));
    }
  }
  float rs[4][4];
#pragma unroll
  for (int m = 0; m < 4; ++m)
#pragma unroll
    for (int j = 0; j < 4; ++j) {
      const int qi = m * 16 + lhi * 4 + j;
      int qg = 0;
      if (MASKED) {
        const int y = wy * 8 + (qi >> 3), x = wx * 8 + (qi & 7);
        qg = ((y < 56) ? 0 : ((y < 60) ? 1 : 2)) * 3 + ((x < 56) ? 0 : ((x < 60) ? 1 : 2));
      }
      float mx = -3e38f;
#pragma unroll
      for (int n = 0; n < 4; ++n) {
        float v = s[m][n][j] * 0.125f;
        if (MASKED && kg[n] != qg) v -= 1e9f;
        s[m][n][j] = v;
        mx = fmaxf(mx, v);
      }
#pragma unroll
      for (int d = 1; d < 16; d <<= 1) mx = fmaxf(mx, __shfl_xor(mx, d));
      float sm = 0.f;
#pragma unroll
      for (int n = 0; n < 4; ++n) {
        const float e = __expf(s[m][n][j] - mx);
        s[m][n][j] = e;
        sm += e;
      }
#pragma unroll
      for (int d = 1; d < 16; d <<= 1) sm += __shfl_xor(sm, d);
      rs[m][j] = sm;
    }

#pragma unroll
  for (int m = 0; m < 4; ++m)
#pragma unroll
    for (int j = 0; j < 4; ++j) {
      const int qi = m * 16 + lhi * 4 + j;
#pragma unroll
      for (int n = 0; n < 4; ++n) {
        const int kc = n * 16 + llo;
        *(unsigned short*)(Kb + qi * 128 + (((kc >> 3) ^ (qi & 7)) << 4) + (kc & 7) * 2) =
            f2b(s[m][n][j]);
      }
    }
#pragma unroll
  for (int it = 0; it < 8; ++it) {
    const int r = it * 8 + lr;   // key index
    const unsigned short* pv = (const unsigned short*)&vv[it];
#pragma unroll
    for (int e = 0; e < 8; ++e) {
      const int d = lc * 8 + e;  // dh index
      *(unsigned short*)(Qb + d * 128 + (((r >> 3) ^ (d & 7)) << 4) + (r & 7) * 2) = pv[e];
    }
  }

  f32x4 o[4][4] = {};
#pragma unroll
  for (int ks = 0; ks < 2; ++ks) {
    bf16x8 ap[4], bv[4];
#pragma unroll
    for (int m = 0; m < 4; ++m) {
      const int r = m * 16 + llo;
      const int sl = (ks * 4 + lhi) ^ (r & 7);
      ap[m] = *(const bf16x8*)(Kb + r * 128 + sl * 16);
    }
#pragma unroll
    for (int n = 0; n < 4; ++n) {
      const int r = n * 16 + llo;
      const int sl = (ks * 4 + lhi) ^ (r & 7);
      bv[n] = *(const bf16x8*)(Qb + r * 128 + sl * 16);
    }
#pragma unroll
    for (int m = 0; m < 4; ++m)
#pragma unroll
      for (int n = 0; n < 4; ++n)
        o[m][n] = __builtin_amdgcn_mfma_f32_16x16x32_bf16(ap[m], bv[n], o[m][n], 0, 0, 0);
  }

#pragma unroll
  for (int m = 0; m < 4; ++m)
#pragma unroll
    for (int j = 0; j < 4; ++j) {
      const int qi = m * 16 + lhi * 4 + j;
      int y = wy * 8 + (qi >> 3), x = wx * 8 + (qi & 7);
      if (MASKED) { y = (y + 4) & 63; x = (x + 4) & 63; }
      const size_t prow = (size_t)batch * 4096 + y * 64 + x;
      const float inv = 1.0f / rs[m][j];
#pragma unroll
      for (int n = 0; n < 4; ++n)
        out[prow * 1024 + head * 64 + n * 16 + llo] = f2b(o[m][n][j] * inv);
    }
}

// ---------------------------------------------------------------------------
// Host orchestration — ws-size-adaptive chunking.
// Fixed: weights 48MB @0, F2 fp32 64MB @48MB, X bf16 32MB @112MB.
// Scratch region S @144MB holds qkv+attnout OR mlp mid, sized NB*32MB
// (NB = batches per chunk, chosen from ws_size; same every call).
// F1 (fp32 residual: inp1 / out1) lives in d_out (fully overwritten at end).
// ---------------------------------------------------------------------------
extern "C" void kernel_launch(void* const* d_in, const int* in_sizes, int n_in,
                              void* d_out, int out_size, void* d_ws, size_t ws_size,
                              hipStream_t stream) {
  (void)in_sizes; (void)n_in; (void)out_size;
  const float* x       = (const float*)d_in[0];
  const float* ln1g    = (const float*)d_in[1];
  const float* ln1b    = (const float*)d_in[2];
  const float* ln2g    = (const float*)d_in[3];
  const float* ln2b    = (const float*)d_in[4];
  const float* ln3g    = (const float*)d_in[5];
  const float* ln3b    = (const float*)d_in[6];
  const float* ln4g    = (const float*)d_in[7];
  const float* ln4b    = (const float*)d_in[8];
  const float* mlp1a_w = (const float*)d_in[9];
  const float* mlp1a_b = (const float*)d_in[10];
  const float* mlp2a_w = (const float*)d_in[11];
  const float* mlp2a_b = (const float*)d_in[12];
  const float* mlp1b_w = (const float*)d_in[13];
  const float* mlp1b_b = (const float*)d_in[14];
  const float* mlp2b_w = (const float*)d_in[15];
  const float* mlp2b_b = (const float*)d_in[16];
  const float* a1_wqkv = (const float*)d_in[17];
  const float* a1_bqkv = (const float*)d_in[18];
  const float* a1_wo   = (const float*)d_in[19];
  const float* a1_bo   = (const float*)d_in[20];
  const float* a2_wqkv = (const float*)d_in[21];
  const float* a2_bqkv = (const float*)d_in[22];
  const float* a2_wo   = (const float*)d_in[23];
  const float* a2_bo   = (const float*)d_in[24];

  const size_t MB = 1048576;
  char* ws = (char*)d_ws;
  unsigned short* wqkv1T = (unsigned short*)(ws);
  unsigned short* wo1T   = (unsigned short*)(ws + 6291456);
  unsigned short* wm1aT  = (unsigned short*)(ws + 8388608);
  unsigned short* wm1bT  = (unsigned short*)(ws + 16777216);
  unsigned short* wqkv2T = (unsigned short*)(ws + 25165824);
  unsigned short* wo2T   = (unsigned short*)(ws + 31457280);
  unsigned short* wm2aT  = (unsigned short*)(ws + 33554432);
  unsigned short* wm2bT  = (unsigned short*)(ws + 41943040);
  float*          F2     = (float*)(ws + 48 * MB);
  unsigned short* X      = (unsigned short*)(ws + 112 * MB);
  char*           S      = ws + 144 * MB;
  float*          F1     = (float*)d_out;   // fp32 residual stream (inp1/out1)

  // chunk factor from available scratch (stable per session -> graph-safe)
  const size_t avail = ws_size > 144 * MB ? ws_size - 144 * MB : 0;
  const int NB = (avail >= 128 * MB) ? 4 : (avail >= 64 * MB) ? 2 : 1;
  const int MC = NB * 4096;                            // rows per chunk
  unsigned short* Sq = (unsigned short*)S;             // qkv chunk (NB*24MB)
  unsigned short* Sa = (unsigned short*)(S + (size_t)MC * 3072 * 2);  // attn out
  unsigned short* Sm = (unsigned short*)S;             // mlp mid chunk (NB*32MB)

  const dim3 tb(32, 8);
  wconv<<<dim3(96, 32), tb, 0, stream>>>(a1_wqkv, wqkv1T, 1024, 3072);
  wconv<<<dim3(32, 32), tb, 0, stream>>>(a1_wo, wo1T, 1024, 1024);
  wconv<<<dim3(128, 32), tb, 0, stream>>>(mlp1a_w, wm1aT, 1024, 4096);
  wconv<<<dim3(32, 128), tb, 0, stream>>>(mlp1b_w, wm1bT, 4096, 1024);
  wconv<<<dim3(96, 32), tb, 0, stream>>>(a2_wqkv, wqkv2T, 1024, 3072);
  wconv<<<dim3(32, 32), tb, 0, stream>>>(a2_wo, wo2T, 1024, 1024);
  wconv<<<dim3(128, 32), tb, 0, stream>>>(mlp2a_w, wm2aT, 1024, 4096);
  wconv<<<dim3(32, 128), tb, 0, stream>>>(mlp2b_w, wm2bT, 4096, 1024);

  // ---- layer 1: W-MSA ----
  ln_fused<<<16384, 256, 0, stream>>>(x, ln1g, ln1b, F1, X);              // inp1
  for (int b = 0; b < 4; b += NB) {
    const size_t r0 = (size_t)b * 4096;
    gemm_bt<0><<<(MC / 128) * 24, 256, 0, stream>>>(X + r0 * 1024, wqkv1T,
        a1_bqkv, nullptr, Sq, MC, 3072, 1024);
    attn_win<0><<<NB * 256, 256, 0, stream>>>(Sq, Sa);
    gemm_bt<1><<<(MC / 128) * 8, 256, 0, stream>>>(Sa, wo1T, a1_bo,
        F1 + r0 * 1024, F2 + r0 * 1024, MC, 1024, 1024);                  // w
  }
  // ---- layer 1: MLP ----
  ln_fused<<<16384, 256, 0, stream>>>(F2, ln2g, ln2b, nullptr, X);
  for (int c = 0; c < 4; c += NB) {
    const size_t r0 = (size_t)c * 4096;
    gemm_bt<0><<<(MC / 128) * 32, 256, 0, stream>>>(X + r0 * 1024, wm1aT,
        mlp1a_b, nullptr, Sm, MC, 4096, 1024);
    gemm_bt<1><<<(MC / 128) * 8, 256, 0, stream>>>(Sm, wm1bT, mlp1b_b,
        F2 + r0 * 1024, F1 + r0 * 1024, MC, 1024, 4096);                  // out1
  }

  // ---- layer 2: SW-MSA ----
  ln_fused<<<16384, 256, 0, stream>>>(F1, ln3g, ln3b, nullptr, X);        // inp2
  for (int b = 0; b < 4; b += NB) {
    const size_t r0 = (size_t)b * 4096;
    gemm_bt<0><<<(MC / 128) * 24, 256, 0, stream>>>(X + r0 * 1024, wqkv2T,
        a2_bqkv, nullptr, Sq, MC, 3072, 1024);
    attn_win<1><<<NB * 256, 256, 0, stream>>>(Sq, Sa);
    gemm_bt<1><<<(MC / 128) * 8, 256, 0, stream>>>(Sa, wo2T, a2_bo,
        F1 + r0 * 1024, F2 + r0 * 1024, MC, 1024, 1024);                  // sw
  }
  // ---- layer 2: MLP ----
  ln_fused<<<16384, 256, 0, stream>>>(F2, ln4g, ln4b, nullptr, X);
  for (int c = 0; c < 4; c += NB) {
    const size_t r0 = (size_t)c * 4096;
    gemm_bt<0><<<(MC / 128) * 32, 256, 0, stream>>>(X + r0 * 1024, wm2aT,
        mlp2a_b, nullptr, Sm, MC, 4096, 1024);
    gemm_bt<1><<<(MC / 128) * 8, 256, 0, stream>>>(Sm, wm2bT, mlp2b_b,
        F2 + r0 * 1024, F1 + r0 * 1024, MC, 1024, 4096);                  // out2
  }
}

// Round 4
// 1404.279 us; speedup vs baseline: 1.0297x; 1.0297x over previous
//
#include <hip/hip_runtime.h>

// ---------------------------------------------------------------------------
// Swin block (BS=4, GRID=64, D=1024, WS=8, NH=16) on MI355X.
// bf16 MFMA GEMMs (fp32 accumulate), fp32 residual/LN/softmax.
// Round 4: ring-pipelined GEMM (T3+T4+T5): 128x256 tile, 8 waves, LDS ring of
// 5 K=32 slots (120KB), counted vmcnt(9) never draining to 0 in main loop,
// raw s_barrier, setprio around MFMA cluster. Swizzle identical to verified
// round-3 kernel (0 bank conflicts measured).
// ---------------------------------------------------------------------------

typedef __bf16 bf16x8 __attribute__((ext_vector_type(8)));
typedef float f32x4 __attribute__((ext_vector_type(4)));

__device__ __forceinline__ unsigned short f2b(float x) {
  union { float f; unsigned u; } c; c.f = x;
  unsigned r = c.u + 0x7fffu + ((c.u >> 16) & 1u);   // RNE
  return (unsigned short)(r >> 16);
}

__device__ __forceinline__ void gload16(const void* gp, void* lp) {
  __builtin_amdgcn_global_load_lds(
      (const __attribute__((address_space(1))) void*)gp,
      (__attribute__((address_space(3))) void*)lp, 16, 0, 0);
}

// ---------------------------------------------------------------------------
// Weight convert: fp32 [K][N] -> bf16 [N][K]  (transpose + cast), 32x32 tiles.
// ---------------------------------------------------------------------------
__global__ void wconv(const float* __restrict__ src, unsigned short* __restrict__ dst,
                      int K, int N) {
  __shared__ float t[32][33];
  const int tx = threadIdx.x, ty = threadIdx.y;
  const int n0 = blockIdx.x * 32, k0 = blockIdx.y * 32;
#pragma unroll
  for (int i = 0; i < 4; ++i)
    t[ty + i * 8][tx] = src[(size_t)(k0 + ty + i * 8) * N + n0 + tx];
  __syncthreads();
#pragma unroll
  for (int i = 0; i < 4; ++i)
    dst[(size_t)(n0 + ty + i * 8) * K + k0 + tx] = f2b(t[tx][ty + i * 8]);
}

// ---------------------------------------------------------------------------
// LayerNorm over D=1024; optional fp32 copy + bf16 copy (GEMM A input).
// ---------------------------------------------------------------------------
__global__ __launch_bounds__(256) void ln_fused(
    const float* __restrict__ in, const float* __restrict__ gw,
    const float* __restrict__ bw, float* __restrict__ outf,
    unsigned short* __restrict__ outb) {
  const int row = blockIdx.x;
  const int t = threadIdx.x;
  const int w = t >> 6, l = t & 63;
  const float4 v = ((const float4*)(in + (size_t)row * 1024))[t];
  float s1 = v.x + v.y + v.z + v.w;
  float s2 = v.x * v.x + v.y * v.y + v.z * v.z + v.w * v.w;
#pragma unroll
  for (int d = 32; d >= 1; d >>= 1) { s1 += __shfl_down(s1, d); s2 += __shfl_down(s2, d); }
  __shared__ float red[8];
  if (l == 0) { red[w] = s1; red[4 + w] = s2; }
  __syncthreads();
  const float S1 = red[0] + red[1] + red[2] + red[3];
  const float S2 = red[4] + red[5] + red[6] + red[7];
  const float mu = S1 * (1.0f / 1024.0f);
  const float rsg = rsqrtf(S2 * (1.0f / 1024.0f) - mu * mu + 1e-5f);
  const float4 g4 = ((const float4*)gw)[t];
  const float4 b4 = ((const float4*)bw)[t];
  float4 y;
  y.x = (v.x - mu) * rsg * g4.x + b4.x;
  y.y = (v.y - mu) * rsg * g4.y + b4.y;
  y.z = (v.z - mu) * rsg * g4.z + b4.z;
  y.w = (v.w - mu) * rsg * g4.w + b4.w;
  if (outf) ((float4*)(outf + (size_t)row * 1024))[t] = y;
  ushort4 ob;
  ob.x = f2b(y.x); ob.y = f2b(y.y); ob.z = f2b(y.z); ob.w = f2b(y.w);
  ((ushort4*)(outb + (size_t)row * 1024))[t] = ob;
}

// ---------------------------------------------------------------------------
// Ring-pipelined bf16 GEMM: C = A[M,K] @ B (BT[N,K]).
// Tile 128(M) x 256(N), 8 waves (2x4), per-wave 64x64 (4x4 frags 16x16x32).
// LDS: ring of 5 slots, each = A[128][32] (8KB) + B[256][32] (16KB) = 24KB.
// Per iter: vmcnt(9) -> s_barrier -> stage slot s+4 (3 gload_lds w16) ->
// 8 ds_read_b128 (XOR-swizzled) -> setprio(1) 16 MFMA setprio(0).
// Loads never drain to 0 in the main loop (T4); tail peels 9/6/3/0.
// EPI 0: bf16 out (+bias). EPI 1: fp32 out (+bias +residual).
// ---------------------------------------------------------------------------
#define VMWAIT(N) asm volatile("s_waitcnt vmcnt(" #N ")" ::: "memory")

#define GSTEP(VMC, STG, KS)                                                    \
  {                                                                            \
    VMWAIT(VMC);                                                               \
    __builtin_amdgcn_s_barrier();                                              \
    if (STG) {                                                                 \
      const size_t ko = (size_t)(KS) * 32;                                     \
      gload16(A + a_src + ko, lds + ro_s + lds_lane);                          \
      gload16(BT + b_src0 + ko, lds + ro_s + 8192 + lds_lane);                 \
      gload16(BT + b_src1 + ko, lds + ro_s + 16384 + lds_lane);                \
      ro_s += 24576; if (ro_s == 122880) ro_s = 0;                             \
    }                                                                          \
    bf16x8 af[4], bf[4];                                                       \
    _Pragma("unroll")                                                          \
    for (int m = 0; m < 4; ++m) af[m] = *(const bf16x8*)(lds + ro_r + a_rd[m]);\
    _Pragma("unroll")                                                          \
    for (int n = 0; n < 4; ++n) bf[n] = *(const bf16x8*)(lds + ro_r + b_rd[n]);\
    __builtin_amdgcn_s_setprio(1);                                             \
    _Pragma("unroll")                                                          \
    for (int m = 0; m < 4; ++m)                                                \
      _Pragma("unroll")                                                        \
      for (int n = 0; n < 4; ++n)                                              \
        acc[m][n] = __builtin_amdgcn_mfma_f32_16x16x32_bf16(af[m], bf[n],      \
                                                            acc[m][n], 0, 0, 0);\
    __builtin_amdgcn_s_setprio(0);                                             \
    ro_r += 24576; if (ro_r == 122880) ro_r = 0;                               \
  }

template <int EPI>
__global__ __launch_bounds__(512, 2) void gemm_ring(
    const unsigned short* __restrict__ A, const unsigned short* __restrict__ BT,
    const float* __restrict__ bias, const float* __restrict__ res,
    void* __restrict__ Cout, int M, int N, int K) {
  __shared__ __align__(16) char lds[122880];   // 5 x 24KB ring
  const int tid = threadIdx.x;
  const int w = tid >> 6, l = tid & 63;
  const int lhi = l >> 4, llo = l & 15;
  // T1: XCD swizzle (all grids %8 == 0)
  const int cpx = gridDim.x >> 3;
  const int bid = (blockIdx.x & 7) * cpx + (blockIdx.x >> 3);
  const int tiles_n = N >> 8;
  const int tm = bid / tiles_n;
  const int tn = bid - tm * tiles_n;
  const int wr = w >> 2, wc = w & 3;           // 2 x 4 waves, per-wave 64x64

  // staging source (pre-swizzled granules; involution g ^= (row>>1)&3)
  const int ga_row = tid >> 2;
  const int ga_g = (tid & 3) ^ ((ga_row >> 1) & 3);
  const size_t a_src = (size_t)(tm * 128 + ga_row) * K + ga_g * 8;
  const int gb0_row = tid >> 2;
  const int gb0_g = (tid & 3) ^ ((gb0_row >> 1) & 3);
  const size_t b_src0 = (size_t)(tn * 256 + gb0_row) * K + gb0_g * 8;
  const int gb1_row = (512 + tid) >> 2;
  const int gb1_g = (tid & 3) ^ ((gb1_row >> 1) & 3);
  const size_t b_src1 = (size_t)(tn * 256 + gb1_row) * K + gb1_g * 8;
  const int lds_lane = w * 1024;               // wave-uniform LDS base

  // swizzled ds_read offsets within a slot (rows of 64B, 4 granules)
  int a_rd[4], b_rd[4];
#pragma unroll
  for (int m = 0; m < 4; ++m) {
    const int row = wr * 64 + m * 16 + llo;
    a_rd[m] = row * 64 + ((lhi ^ ((row >> 1) & 3)) << 4);
  }
#pragma unroll
  for (int n = 0; n < 4; ++n) {
    const int row = wc * 64 + n * 16 + llo;
    b_rd[n] = 8192 + row * 64 + ((lhi ^ ((row >> 1) & 3)) << 4);
  }

  // prologue: stage slots 0..3 (12 gload in flight)
  int ro_s = 0;
#pragma unroll
  for (int p = 0; p < 4; ++p) {
    const size_t ko = (size_t)p * 32;
    gload16(A + a_src + ko, lds + ro_s + lds_lane);
    gload16(BT + b_src0 + ko, lds + ro_s + 8192 + lds_lane);
    gload16(BT + b_src1 + ko, lds + ro_s + 16384 + lds_lane);
    ro_s += 24576;
  }
  int ro_r = 0;

  f32x4 acc[4][4] = {};
  const int ns = K >> 5;                        // K=1024 -> 32, K=4096 -> 128
  for (int s = 0; s < ns - 4; ++s) GSTEP(9, 1, s + 4);
  GSTEP(9, 0, 0);
  GSTEP(6, 0, 0);
  GSTEP(3, 0, 0);
  GSTEP(0, 0, 0);

  // epilogue: C/D layout col=lane&15, row=(lane>>4)*4+j
  const int row0 = tm * 128 + wr * 64 + lhi * 4;
  const int col0 = tn * 256 + wc * 64 + llo;
#pragma unroll
  for (int m = 0; m < 4; ++m)
#pragma unroll
    for (int j = 0; j < 4; ++j) {
      const int rowg = row0 + m * 16 + j;
#pragma unroll
      for (int n = 0; n < 4; ++n) {
        const int colg = col0 + n * 16;
        float v = acc[m][n][j] + bias[colg];
        if (EPI == 1) {
          v += res[(size_t)rowg * N + colg];
          ((float*)Cout)[(size_t)rowg * N + colg] = v;
        } else {
          ((unsigned short*)Cout)[(size_t)rowg * N + colg] = f2b(v);
        }
      }
    }
}

// ---------------------------------------------------------------------------
// Windowed MHSA: one wave per (window, head); 4 heads/block. Chunk-local
// batches. MASKED=1: roll via (y+4)&63 on load/store, mask groups from
// ROLLED coords (56/60 boundaries).
// ---------------------------------------------------------------------------
template <int MASKED>
__global__ __launch_bounds__(256, 2) void attn_win(
    const unsigned short* __restrict__ qkv, unsigned short* __restrict__ out) {
  __shared__ __align__(16) char lds[65536];
  const int tid = threadIdx.x;
  const int w = tid >> 6, l = tid & 63;
  const int lhi = l >> 4, llo = l & 15;
  const int head = ((blockIdx.x & 3) << 2) | w;
  const int widx = blockIdx.x >> 2;
  const int batch = widx >> 6;
  const int wy = (widx >> 3) & 7, wx = widx & 7;
  char* Qb = lds + w * 16384;   // Q, later V^T
  char* Kb = Qb + 8192;         // K, later P
  const int lr = l >> 3, lc = l & 7;

  uint4 vv[8];
#pragma unroll
  for (int it = 0; it < 8; ++it) {
    const int r = it * 8 + lr;
    int y = wy * 8 + (r >> 3), x = wx * 8 + (r & 7);
    if (MASKED) { y = (y + 4) & 63; x = (x + 4) & 63; }
    const size_t base = ((size_t)batch * 4096 + y * 64 + x) * 3072 + head * 64 + lc * 8;
    const uint4 qv = *(const uint4*)(qkv + base);
    const uint4 kv = *(const uint4*)(qkv + base + 1024);
    vv[it] = *(const uint4*)(qkv + base + 2048);
    const int sl = lc ^ (r & 7);
    *(uint4*)(Qb + r * 128 + sl * 16) = qv;
    *(uint4*)(Kb + r * 128 + sl * 16) = kv;
  }

  f32x4 s[4][4] = {};
#pragma unroll
  for (int ks = 0; ks < 2; ++ks) {
    bf16x8 aq[4], bk[4];
#pragma unroll
    for (int m = 0; m < 4; ++m) {
      const int r = m * 16 + llo;
      const int sl = (ks * 4 + lhi) ^ (r & 7);
      aq[m] = *(const bf16x8*)(Qb + r * 128 + sl * 16);
    }
#pragma unroll
    for (int n = 0; n < 4; ++n) {
      const int r = n * 16 + llo;
      const int sl = (ks * 4 + lhi) ^ (r & 7);
      bk[n] = *(const bf16x8*)(Kb + r * 128 + sl * 16);
    }
#pragma unroll
    for (int m = 0; m < 4; ++m)
#pragma unroll
      for (int n = 0; n < 4; ++n)
        s[m][n] = __builtin_amdgcn_mfma_f32_16x16x32_bf16(aq[m], bk[n], s[m][n], 0, 0, 0);
  }

  int kg[4] = {0, 0, 0, 0};
  if (MASKED) {
#pragma unroll
    for (int n = 0; n < 4; ++n) {
      const int p = n * 16 + llo;
      const int y = wy * 8 + (p >> 3), x = wx * 8 + (p & 7);
      kg[n] = ((y < 56) ? 0 : ((y < 60) ? 1 : 2)) * 3 + ((x < 56) ? 0 : ((x < 60) ? 1 : 2));
    }
  }
  float rs[4][4];
#pragma unroll
  for (int m = 0; m < 4; ++m)
#pragma unroll
    for (int j = 0; j < 4; ++j) {
      const int qi = m * 16 + lhi * 4 + j;
      int qg = 0;
      if (MASKED) {
        const int y = wy * 8 + (qi >> 3), x = wx * 8 + (qi & 7);
        qg = ((y < 56) ? 0 : ((y < 60) ? 1 : 2)) * 3 + ((x < 56) ? 0 : ((x < 60) ? 1 : 2));
      }
      float mx = -3e38f;
#pragma unroll
      for (int n = 0; n < 4; ++n) {
        float v = s[m][n][j] * 0.125f;
        if (MASKED && kg[n] != qg) v -= 1e9f;
        s[m][n][j] = v;
        mx = fmaxf(mx, v);
      }
#pragma unroll
      for (int d = 1; d < 16; d <<= 1) mx = fmaxf(mx, __shfl_xor(mx, d));
      float sm = 0.f;
#pragma unroll
      for (int n = 0; n < 4; ++n) {
        const float e = __expf(s[m][n][j] - mx);
        s[m][n][j] = e;
        sm += e;
      }
#pragma unroll
      for (int d = 1; d < 16; d <<= 1) sm += __shfl_xor(sm, d);
      rs[m][j] = sm;
    }

#pragma unroll
  for (int m = 0; m < 4; ++m)
#pragma unroll
    for (int j = 0; j < 4; ++j) {
      const int qi = m * 16 + lhi * 4 + j;
#pragma unroll
      for (int n = 0; n < 4; ++n) {
        const int kc = n * 16 + llo;
        *(unsigned short*)(Kb + qi * 128 + (((kc >> 3) ^ (qi & 7)) << 4) + (kc & 7) * 2) =
            f2b(s[m][n][j]);
      }
    }
#pragma unroll
  for (int it = 0; it < 8; ++it) {
    const int r = it * 8 + lr;   // key index
    const unsigned short* pv = (const unsigned short*)&vv[it];
#pragma unroll
    for (int e = 0; e < 8; ++e) {
      const int d = lc * 8 + e;  // dh index
      *(unsigned short*)(Qb + d * 128 + (((r >> 3) ^ (d & 7)) << 4) + (r & 7) * 2) = pv[e];
    }
  }

  f32x4 o[4][4] = {};
#pragma unroll
  for (int ks = 0; ks < 2; ++ks) {
    bf16x8 ap[4], bv[4];
#pragma unroll
    for (int m = 0; m < 4; ++m) {
      const int r = m * 16 + llo;
      const int sl = (ks * 4 + lhi) ^ (r & 7);
      ap[m] = *(const bf16x8*)(Kb + r * 128 + sl * 16);
    }
#pragma unroll
    for (int n = 0; n < 4; ++n) {
      const int r = n * 16 + llo;
      const int sl = (ks * 4 + lhi) ^ (r & 7);
      bv[n] = *(const bf16x8*)(Qb + r * 128 + sl * 16);
    }
#pragma unroll
    for (int m = 0; m < 4; ++m)
#pragma unroll
      for (int n = 0; n < 4; ++n)
        o[m][n] = __builtin_amdgcn_mfma_f32_16x16x32_bf16(ap[m], bv[n], o[m][n], 0, 0, 0);
  }

#pragma unroll
  for (int m = 0; m < 4; ++m)
#pragma unroll
    for (int j = 0; j < 4; ++j) {
      const int qi = m * 16 + lhi * 4 + j;
      int y = wy * 8 + (qi >> 3), x = wx * 8 + (qi & 7);
      if (MASKED) { y = (y + 4) & 63; x = (x + 4) & 63; }
      const size_t prow = (size_t)batch * 4096 + y * 64 + x;
      const float inv = 1.0f / rs[m][j];
#pragma unroll
      for (int n = 0; n < 4; ++n)
        out[prow * 1024 + head * 64 + n * 16 + llo] = f2b(o[m][n][j] * inv);
    }
}

// ---------------------------------------------------------------------------
// Host orchestration — ws-size-adaptive chunking (same plan as the passing
// round-3 run: fixed 144MB + NB*32MB scratch; F1 residual lives in d_out).
// ---------------------------------------------------------------------------
extern "C" void kernel_launch(void* const* d_in, const int* in_sizes, int n_in,
                              void* d_out, int out_size, void* d_ws, size_t ws_size,
                              hipStream_t stream) {
  (void)in_sizes; (void)n_in; (void)out_size;
  const float* x       = (const float*)d_in[0];
  const float* ln1g    = (const float*)d_in[1];
  const float* ln1b    = (const float*)d_in[2];
  const float* ln2g    = (const float*)d_in[3];
  const float* ln2b    = (const float*)d_in[4];
  const float* ln3g    = (const float*)d_in[5];
  const float* ln3b    = (const float*)d_in[6];
  const float* ln4g    = (const float*)d_in[7];
  const float* ln4b    = (const float*)d_in[8];
  const float* mlp1a_w = (const float*)d_in[9];
  const float* mlp1a_b = (const float*)d_in[10];
  const float* mlp2a_w = (const float*)d_in[11];
  const float* mlp2a_b = (const float*)d_in[12];
  const float* mlp1b_w = (const float*)d_in[13];
  const float* mlp1b_b = (const float*)d_in[14];
  const float* mlp2b_w = (const float*)d_in[15];
  const float* mlp2b_b = (const float*)d_in[16];
  const float* a1_wqkv = (const float*)d_in[17];
  const float* a1_bqkv = (const float*)d_in[18];
  const float* a1_wo   = (const float*)d_in[19];
  const float* a1_bo   = (const float*)d_in[20];
  const float* a2_wqkv = (const float*)d_in[21];
  const float* a2_bqkv = (const float*)d_in[22];
  const float* a2_wo   = (const float*)d_in[23];
  const float* a2_bo   = (const float*)d_in[24];

  const size_t MB = 1048576;
  char* ws = (char*)d_ws;
  unsigned short* wqkv1T = (unsigned short*)(ws);
  unsigned short* wo1T   = (unsigned short*)(ws + 6291456);
  unsigned short* wm1aT  = (unsigned short*)(ws + 8388608);
  unsigned short* wm1bT  = (unsigned short*)(ws + 16777216);
  unsigned short* wqkv2T = (unsigned short*)(ws + 25165824);
  unsigned short* wo2T   = (unsigned short*)(ws + 31457280);
  unsigned short* wm2aT  = (unsigned short*)(ws + 33554432);
  unsigned short* wm2bT  = (unsigned short*)(ws + 41943040);
  float*          F2     = (float*)(ws + 48 * MB);
  unsigned short* X      = (unsigned short*)(ws + 112 * MB);
  char*           S      = ws + 144 * MB;
  float*          F1     = (float*)d_out;   // fp32 residual stream (inp1/out1)

  const size_t avail = ws_size > 144 * MB ? ws_size - 144 * MB : 0;
  const int NB = (avail >= 128 * MB) ? 4 : (avail >= 64 * MB) ? 2 : 1;
  const int MC = NB * 4096;                            // rows per chunk
  const int MT = MC / 128;                             // M-tiles per chunk
  unsigned short* Sq = (unsigned short*)S;             // qkv chunk (NB*24MB)
  unsigned short* Sa = (unsigned short*)(S + (size_t)MC * 3072 * 2);  // attn out
  unsigned short* Sm = (unsigned short*)S;             // mlp mid chunk (NB*32MB)

  const dim3 tb(32, 8);
  wconv<<<dim3(96, 32), tb, 0, stream>>>(a1_wqkv, wqkv1T, 1024, 3072);
  wconv<<<dim3(32, 32), tb, 0, stream>>>(a1_wo, wo1T, 1024, 1024);
  wconv<<<dim3(128, 32), tb, 0, stream>>>(mlp1a_w, wm1aT, 1024, 4096);
  wconv<<<dim3(32, 128), tb, 0, stream>>>(mlp1b_w, wm1bT, 4096, 1024);
  wconv<<<dim3(96, 32), tb, 0, stream>>>(a2_wqkv, wqkv2T, 1024, 3072);
  wconv<<<dim3(32, 32), tb, 0, stream>>>(a2_wo, wo2T, 1024, 1024);
  wconv<<<dim3(128, 32), tb, 0, stream>>>(mlp2a_w, wm2aT, 1024, 4096);
  wconv<<<dim3(32, 128), tb, 0, stream>>>(mlp2b_w, wm2bT, 4096, 1024);

  // ---- layer 1: W-MSA ----
  ln_fused<<<16384, 256, 0, stream>>>(x, ln1g, ln1b, F1, X);              // inp1
  for (int b = 0; b < 4; b += NB) {
    const size_t r0 = (size_t)b * 4096;
    gemm_ring<0><<<MT * 12, 512, 0, stream>>>(X + r0 * 1024, wqkv1T,
        a1_bqkv, nullptr, Sq, MC, 3072, 1024);
    attn_win<0><<<NB * 256, 256, 0, stream>>>(Sq, Sa);
    gemm_ring<1><<<MT * 4, 512, 0, stream>>>(Sa, wo1T, a1_bo,
        F1 + r0 * 1024, F2 + r0 * 1024, MC, 1024, 1024);                  // w
  }
  // ---- layer 1: MLP ----
  ln_fused<<<16384, 256, 0, stream>>>(F2, ln2g, ln2b, nullptr, X);
  for (int c = 0; c < 4; c += NB) {
    const size_t r0 = (size_t)c * 4096;
    gemm_ring<0><<<MT * 16, 512, 0, stream>>>(X + r0 * 1024, wm1aT,
        mlp1a_b, nullptr, Sm, MC, 4096, 1024);
    gemm_ring<1><<<MT * 4, 512, 0, stream>>>(Sm, wm1bT, mlp1b_b,
        F2 + r0 * 1024, F1 + r0 * 1024, MC, 1024, 4096);                  // out1
  }

  // ---- layer 2: SW-MSA ----
  ln_fused<<<16384, 256, 0, stream>>>(F1, ln3g, ln3b, nullptr, X);        // inp2
  for (int b = 0; b < 4; b += NB) {
    const size_t r0 = (size_t)b * 4096;
    gemm_ring<0><<<MT * 12, 512, 0, stream>>>(X + r0 * 1024, wqkv2T,
        a2_bqkv, nullptr, Sq, MC, 3072, 1024);
    attn_win<1><<<NB * 256, 256, 0, stream>>>(Sq, Sa);
    gemm_ring<1><<<MT * 4, 512, 0, stream>>>(Sa, wo2T, a2_bo,
        F1 + r0 * 1024, F2 + r0 * 1024, MC, 1024, 1024);                  // sw
  }
  // ---- layer 2: MLP ----
  ln_fused<<<16384, 256, 0, stream>>>(F2, ln4g, ln4b, nullptr, X);
  for (int c = 0; c < 4; c += NB) {
    const size_t r0 = (size_t)c * 4096;
    gemm_ring<0><<<MT * 16, 512, 0, stream>>>(X + r0 * 1024, wm2aT,
        mlp2a_b, nullptr, Sm, MC, 4096, 1024);
    gemm_ring<1><<<MT * 4, 512, 0, stream>>>(Sm, wm2bT, mlp2b_b,
        F2 + r0 * 1024, F1 + r0 * 1024, MC, 1024, 4096);                  // out2
  }
}

// Round 6
// 1344.920 us; speedup vs baseline: 1.0752x; 1.0441x over previous
//
#include <hip/hip_runtime.h>

// ---------------------------------------------------------------------------
// Swin block (BS=4, GRID=64, D=1024, WS=8, NH=16) on MI355X.
// bf16 MFMA GEMMs (fp32 accumulate), fp32 residual/LN/softmax.
// Round 6 (= round-5 resubmission; GPU was unavailable): ring GEMM with 3
// slots (72KB LDS) so 2 blocks/CU co-reside (round-4 had 120KB -> 1 block/CU
// -> barrier stalled the whole CU, MfmaUtil 28%). Counted vmcnt(3) steady
// state, tail 3->0. launch_bounds(512,4). Swizzle identical (0 conflicts
// measured round 3/4).
// ---------------------------------------------------------------------------

typedef __bf16 bf16x8 __attribute__((ext_vector_type(8)));
typedef float f32x4 __attribute__((ext_vector_type(4)));

__device__ __forceinline__ unsigned short f2b(float x) {
  union { float f; unsigned u; } c; c.f = x;
  unsigned r = c.u + 0x7fffu + ((c.u >> 16) & 1u);   // RNE
  return (unsigned short)(r >> 16);
}

__device__ __forceinline__ void gload16(const void* gp, void* lp) {
  __builtin_amdgcn_global_load_lds(
      (const __attribute__((address_space(1))) void*)gp,
      (__attribute__((address_space(3))) void*)lp, 16, 0, 0);
}

// ---------------------------------------------------------------------------
// Weight convert: fp32 [K][N] -> bf16 [N][K]  (transpose + cast), 32x32 tiles.
// ---------------------------------------------------------------------------
__global__ void wconv(const float* __restrict__ src, unsigned short* __restrict__ dst,
                      int K, int N) {
  __shared__ float t[32][33];
  const int tx = threadIdx.x, ty = threadIdx.y;
  const int n0 = blockIdx.x * 32, k0 = blockIdx.y * 32;
#pragma unroll
  for (int i = 0; i < 4; ++i)
    t[ty + i * 8][tx] = src[(size_t)(k0 + ty + i * 8) * N + n0 + tx];
  __syncthreads();
#pragma unroll
  for (int i = 0; i < 4; ++i)
    dst[(size_t)(n0 + ty + i * 8) * K + k0 + tx] = f2b(t[tx][ty + i * 8]);
}

// ---------------------------------------------------------------------------
// LayerNorm over D=1024; optional fp32 copy + bf16 copy (GEMM A input).
// ---------------------------------------------------------------------------
__global__ __launch_bounds__(256) void ln_fused(
    const float* __restrict__ in, const float* __restrict__ gw,
    const float* __restrict__ bw, float* __restrict__ outf,
    unsigned short* __restrict__ outb) {
  const int row = blockIdx.x;
  const int t = threadIdx.x;
  const int w = t >> 6, l = t & 63;
  const float4 v = ((const float4*)(in + (size_t)row * 1024))[t];
  float s1 = v.x + v.y + v.z + v.w;
  float s2 = v.x * v.x + v.y * v.y + v.z * v.z + v.w * v.w;
#pragma unroll
  for (int d = 32; d >= 1; d >>= 1) { s1 += __shfl_down(s1, d); s2 += __shfl_down(s2, d); }
  __shared__ float red[8];
  if (l == 0) { red[w] = s1; red[4 + w] = s2; }
  __syncthreads();
  const float S1 = red[0] + red[1] + red[2] + red[3];
  const float S2 = red[4] + red[5] + red[6] + red[7];
  const float mu = S1 * (1.0f / 1024.0f);
  const float rsg = rsqrtf(S2 * (1.0f / 1024.0f) - mu * mu + 1e-5f);
  const float4 g4 = ((const float4*)gw)[t];
  const float4 b4 = ((const float4*)bw)[t];
  float4 y;
  y.x = (v.x - mu) * rsg * g4.x + b4.x;
  y.y = (v.y - mu) * rsg * g4.y + b4.y;
  y.z = (v.z - mu) * rsg * g4.z + b4.z;
  y.w = (v.w - mu) * rsg * g4.w + b4.w;
  if (outf) ((float4*)(outf + (size_t)row * 1024))[t] = y;
  ushort4 ob;
  ob.x = f2b(y.x); ob.y = f2b(y.y); ob.z = f2b(y.z); ob.w = f2b(y.w);
  ((ushort4*)(outb + (size_t)row * 1024))[t] = ob;
}

// ---------------------------------------------------------------------------
// Ring-pipelined bf16 GEMM: C = A[M,K] @ B (BT[N,K]).
// Tile 128(M) x 256(N), 8 waves (2x4), per-wave 64x64 (4x4 frags 16x16x32).
// LDS: ring of 3 slots, each = A[128][32] (8KB) + B[256][32] (16KB) = 24KB
// -> 72KB total -> 2 blocks/CU (latency cover via co-resident block).
// Per iter: vmcnt(3) -> s_barrier -> stage slot s+2 -> 8 ds_read_b128
// (XOR-swizzled) -> setprio(1) 16 MFMA setprio(0). Tail peels 3/0.
// vmcnt-before-barrier makes "slot s landed" a collective guarantee.
// EPI 0: bf16 out (+bias). EPI 1: fp32 out (+bias +residual).
// ---------------------------------------------------------------------------
#define VMWAIT(N) asm volatile("s_waitcnt vmcnt(" #N ")" ::: "memory")

#define GSTEP(VMC, STG, KS)                                                    \
  {                                                                            \
    VMWAIT(VMC);                                                               \
    __builtin_amdgcn_s_barrier();                                              \
    if (STG) {                                                                 \
      const size_t ko = (size_t)(KS) * 32;                                     \
      gload16(A + a_src + ko, lds + ro_s + lds_lane);                          \
      gload16(BT + b_src0 + ko, lds + ro_s + 8192 + lds_lane);                 \
      gload16(BT + b_src1 + ko, lds + ro_s + 16384 + lds_lane);                \
      ro_s += 24576; if (ro_s == 73728) ro_s = 0;                              \
    }                                                                          \
    bf16x8 af[4], bf[4];                                                       \
    _Pragma("unroll")                                                          \
    for (int m = 0; m < 4; ++m) af[m] = *(const bf16x8*)(lds + ro_r + a_rd[m]);\
    _Pragma("unroll")                                                          \
    for (int n = 0; n < 4; ++n) bf[n] = *(const bf16x8*)(lds + ro_r + b_rd[n]);\
    __builtin_amdgcn_s_setprio(1);                                             \
    _Pragma("unroll")                                                          \
    for (int m = 0; m < 4; ++m)                                                \
      _Pragma("unroll")                                                        \
      for (int n = 0; n < 4; ++n)                                              \
        acc[m][n] = __builtin_amdgcn_mfma_f32_16x16x32_bf16(af[m], bf[n],      \
                                                            acc[m][n], 0, 0, 0);\
    __builtin_amdgcn_s_setprio(0);                                             \
    ro_r += 24576; if (ro_r == 73728) ro_r = 0;                                \
  }

template <int EPI>
__global__ __launch_bounds__(512, 4) void gemm_ring(
    const unsigned short* __restrict__ A, const unsigned short* __restrict__ BT,
    const float* __restrict__ bias, const float* __restrict__ res,
    void* __restrict__ Cout, int M, int N, int K) {
  __shared__ __align__(16) char lds[73728];    // 3 x 24KB ring
  const int tid = threadIdx.x;
  const int w = tid >> 6, l = tid & 63;
  const int lhi = l >> 4, llo = l & 15;
  // T1: XCD swizzle (all grids %8 == 0)
  const int cpx = gridDim.x >> 3;
  const int bid = (blockIdx.x & 7) * cpx + (blockIdx.x >> 3);
  const int tiles_n = N >> 8;
  const int tm = bid / tiles_n;
  const int tn = bid - tm * tiles_n;
  const int wr = w >> 2, wc = w & 3;           // 2 x 4 waves, per-wave 64x64

  // staging source (pre-swizzled granules; involution g ^= (row>>1)&3)
  const int ga_row = tid >> 2;
  const int ga_g = (tid & 3) ^ ((ga_row >> 1) & 3);
  const size_t a_src = (size_t)(tm * 128 + ga_row) * K + ga_g * 8;
  const int gb0_row = tid >> 2;
  const int gb0_g = (tid & 3) ^ ((gb0_row >> 1) & 3);
  const size_t b_src0 = (size_t)(tn * 256 + gb0_row) * K + gb0_g * 8;
  const int gb1_row = (512 + tid) >> 2;
  const int gb1_g = (tid & 3) ^ ((gb1_row >> 1) & 3);
  const size_t b_src1 = (size_t)(tn * 256 + gb1_row) * K + gb1_g * 8;
  const int lds_lane = w * 1024;               // wave-uniform LDS base

  // swizzled ds_read offsets within a slot (rows of 64B, 4 granules)
  int a_rd[4], b_rd[4];
#pragma unroll
  for (int m = 0; m < 4; ++m) {
    const int row = wr * 64 + m * 16 + llo;
    a_rd[m] = row * 64 + ((lhi ^ ((row >> 1) & 3)) << 4);
  }
#pragma unroll
  for (int n = 0; n < 4; ++n) {
    const int row = wc * 64 + n * 16 + llo;
    b_rd[n] = 8192 + row * 64 + ((lhi ^ ((row >> 1) & 3)) << 4);
  }

  // prologue: stage slots 0..1 (6 gload in flight)
  int ro_s = 0;
#pragma unroll
  for (int p = 0; p < 2; ++p) {
    const size_t ko = (size_t)p * 32;
    gload16(A + a_src + ko, lds + ro_s + lds_lane);
    gload16(BT + b_src0 + ko, lds + ro_s + 8192 + lds_lane);
    gload16(BT + b_src1 + ko, lds + ro_s + 16384 + lds_lane);
    ro_s += 24576;
  }
  int ro_r = 0;

  f32x4 acc[4][4] = {};
  const int ns = K >> 5;                        // K=1024 -> 32, K=4096 -> 128
  for (int s = 0; s < ns - 2; ++s) GSTEP(3, 1, s + 2);
  GSTEP(3, 0, 0);
  GSTEP(0, 0, 0);

  // epilogue: C/D layout col=lane&15, row=(lane>>4)*4+j
  const int row0 = tm * 128 + wr * 64 + lhi * 4;
  const int col0 = tn * 256 + wc * 64 + llo;
#pragma unroll
  for (int m = 0; m < 4; ++m)
#pragma unroll
    for (int j = 0; j < 4; ++j) {
      const int rowg = row0 + m * 16 + j;
#pragma unroll
      for (int n = 0; n < 4; ++n) {
        const int colg = col0 + n * 16;
        float v = acc[m][n][j] + bias[colg];
        if (EPI == 1) {
          v += res[(size_t)rowg * N + colg];
          ((float*)Cout)[(size_t)rowg * N + colg] = v;
        } else {
          ((unsigned short*)Cout)[(size_t)rowg * N + colg] = f2b(v);
        }
      }
    }
}

// ---------------------------------------------------------------------------
// Windowed MHSA: one wave per (window, head); 4 heads/block. Chunk-local
// batches. MASKED=1: roll via (y+4)&63 on load/store, mask groups from
// ROLLED coords (56/60 boundaries).
// ---------------------------------------------------------------------------
template <int MASKED>
__global__ __launch_bounds__(256, 2) void attn_win(
    const unsigned short* __restrict__ qkv, unsigned short* __restrict__ out) {
  __shared__ __align__(16) char lds[65536];
  const int tid = threadIdx.x;
  const int w = tid >> 6, l = tid & 63;
  const int lhi = l >> 4, llo = l & 15;
  const int head = ((blockIdx.x & 3) << 2) | w;
  const int widx = blockIdx.x >> 2;
  const int batch = widx >> 6;
  const int wy = (widx >> 3) & 7, wx = widx & 7;
  char* Qb = lds + w * 16384;   // Q, later V^T
  char* Kb = Qb + 8192;         // K, later P
  const int lr = l >> 3, lc = l & 7;

  uint4 vv[8];
#pragma unroll
  for (int it = 0; it < 8; ++it) {
    const int r = it * 8 + lr;
    int y = wy * 8 + (r >> 3), x = wx * 8 + (r & 7);
    if (MASKED) { y = (y + 4) & 63; x = (x + 4) & 63; }
    const size_t base = ((size_t)batch * 4096 + y * 64 + x) * 3072 + head * 64 + lc * 8;
    const uint4 qv = *(const uint4*)(qkv + base);
    const uint4 kv = *(const uint4*)(qkv + base + 1024);
    vv[it] = *(const uint4*)(qkv + base + 2048);
    const int sl = lc ^ (r & 7);
    *(uint4*)(Qb + r * 128 + sl * 16) = qv;
    *(uint4*)(Kb + r * 128 + sl * 16) = kv;
  }

  f32x4 s[4][4] = {};
#pragma unroll
  for (int ks = 0; ks < 2; ++ks) {
    bf16x8 aq[4], bk[4];
#pragma unroll
    for (int m = 0; m < 4; ++m) {
      const int r = m * 16 + llo;
      const int sl = (ks * 4 + lhi) ^ (r & 7);
      aq[m] = *(const bf16x8*)(Qb + r * 128 + sl * 16);
    }
#pragma unroll
    for (int n = 0; n < 4; ++n) {
      const int r = n * 16 + llo;
      const int sl = (ks * 4 + lhi) ^ (r & 7);
      bk[n] = *(const bf16x8*)(Kb + r * 128 + sl * 16);
    }
#pragma unroll
    for (int m = 0; m < 4; ++m)
#pragma unroll
      for (int n = 0; n < 4; ++n)
        s[m][n] = __builtin_amdgcn_mfma_f32_16x16x32_bf16(aq[m], bk[n], s[m][n], 0, 0, 0);
  }

  int kg[4] = {0, 0, 0, 0};
  if (MASKED) {
#pragma unroll
    for (int n = 0; n < 4; ++n) {
      const int p = n * 16 + llo;
      const int y = wy * 8 + (p >> 3), x = wx * 8 + (p & 7);
      kg[n] = ((y < 56) ? 0 : ((y < 60) ? 1 : 2)) * 3 + ((x < 56) ? 0 : ((x < 60) ? 1 : 2));
    }
  }
  float rs[4][4];
#pragma unroll
  for (int m = 0; m < 4; ++m)
#pragma unroll
    for (int j = 0; j < 4; ++j) {
      const int qi = m * 16 + lhi * 4 + j;
      int qg = 0;
      if (MASKED) {
        const int y = wy * 8 + (qi >> 3), x = wx * 8 + (qi & 7);
        qg = ((y < 56) ? 0 : ((y < 60) ? 1 : 2)) * 3 + ((x < 56) ? 0 : ((x < 60) ? 1 : 2));
      }
      float mx = -3e38f;
#pragma unroll
      for (int n = 0; n < 4; ++n) {
        float v = s[m][n][j] * 0.125f;
        if (MASKED && kg[n] != qg) v -= 1e9f;
        s[m][n][j] = v;
        mx = fmaxf(mx, v);
      }
#pragma unroll
      for (int d = 1; d < 16; d <<= 1) mx = fmaxf(mx, __shfl_xor(mx, d));
      float sm = 0.f;
#pragma unroll
      for (int n = 0; n < 4; ++n) {
        const float e = __expf(s[m][n][j] - mx);
        s[m][n][j] = e;
        sm += e;
      }
#pragma unroll
      for (int d = 1; d < 16; d <<= 1) sm += __shfl_xor(sm, d);
      rs[m][j] = sm;
    }

#pragma unroll
  for (int m = 0; m < 4; ++m)
#pragma unroll
    for (int j = 0; j < 4; ++j) {
      const int qi = m * 16 + lhi * 4 + j;
#pragma unroll
      for (int n = 0; n < 4; ++n) {
        const int kc = n * 16 + llo;
        *(unsigned short*)(Kb + qi * 128 + (((kc >> 3) ^ (qi & 7)) << 4) + (kc & 7) * 2) =
            f2b(s[m][n][j]);
      }
    }
#pragma unroll
  for (int it = 0; it < 8; ++it) {
    const int r = it * 8 + lr;   // key index
    const unsigned short* pv = (const unsigned short*)&vv[it];
#pragma unroll
    for (int e = 0; e < 8; ++e) {
      const int d = lc * 8 + e;  // dh index
      *(unsigned short*)(Qb + d * 128 + (((r >> 3) ^ (d & 7)) << 4) + (r & 7) * 2) = pv[e];
    }
  }

  f32x4 o[4][4] = {};
#pragma unroll
  for (int ks = 0; ks < 2; ++ks) {
    bf16x8 ap[4], bv[4];
#pragma unroll
    for (int m = 0; m < 4; ++m) {
      const int r = m * 16 + llo;
      const int sl = (ks * 4 + lhi) ^ (r & 7);
      ap[m] = *(const bf16x8*)(Kb + r * 128 + sl * 16);
    }
#pragma unroll
    for (int n = 0; n < 4; ++n) {
      const int r = n * 16 + llo;
      const int sl = (ks * 4 + lhi) ^ (r & 7);
      bv[n] = *(const bf16x8*)(Qb + r * 128 + sl * 16);
    }
#pragma unroll
    for (int m = 0; m < 4; ++m)
#pragma unroll
      for (int n = 0; n < 4; ++n)
        o[m][n] = __builtin_amdgcn_mfma_f32_16x16x32_bf16(ap[m], bv[n], o[m][n], 0, 0, 0);
  }

#pragma unroll
  for (int m = 0; m < 4; ++m)
#pragma unroll
    for (int j = 0; j < 4; ++j) {
      const int qi = m * 16 + lhi * 4 + j;
      int y = wy * 8 + (qi >> 3), x = wx * 8 + (qi & 7);
      if (MASKED) { y = (y + 4) & 63; x = (x + 4) & 63; }
      const size_t prow = (size_t)batch * 4096 + y * 64 + x;
      const float inv = 1.0f / rs[m][j];
#pragma unroll
      for (int n = 0; n < 4; ++n)
        out[prow * 1024 + head * 64 + n * 16 + llo] = f2b(o[m][n][j] * inv);
    }
}

// ---------------------------------------------------------------------------
// Host orchestration — ws-size-adaptive chunking (plan identical to the
// passing round-3/4 runs; NB=4 confirmed by FETCH_SIZE match).
// ---------------------------------------------------------------------------
extern "C" void kernel_launch(void* const* d_in, const int* in_sizes, int n_in,
                              void* d_out, int out_size, void* d_ws, size_t ws_size,
                              hipStream_t stream) {
  (void)in_sizes; (void)n_in; (void)out_size;
  const float* x       = (const float*)d_in[0];
  const float* ln1g    = (const float*)d_in[1];
  const float* ln1b    = (const float*)d_in[2];
  const float* ln2g    = (const float*)d_in[3];
  const float* ln2b    = (const float*)d_in[4];
  const float* ln3g    = (const float*)d_in[5];
  const float* ln3b    = (const float*)d_in[6];
  const float* ln4g    = (const float*)d_in[7];
  const float* ln4b    = (const float*)d_in[8];
  const float* mlp1a_w = (const float*)d_in[9];
  const float* mlp1a_b = (const float*)d_in[10];
  const float* mlp2a_w = (const float*)d_in[11];
  const float* mlp2a_b = (const float*)d_in[12];
  const float* mlp1b_w = (const float*)d_in[13];
  const float* mlp1b_b = (const float*)d_in[14];
  const float* mlp2b_w = (const float*)d_in[15];
  const float* mlp2b_b = (const float*)d_in[16];
  const float* a1_wqkv = (const float*)d_in[17];
  const float* a1_bqkv = (const float*)d_in[18];
  const float* a1_wo   = (const float*)d_in[19];
  const float* a1_bo   = (const float*)d_in[20];
  const float* a2_wqkv = (const float*)d_in[21];
  const float* a2_bqkv = (const float*)d_in[22];
  const float* a2_wo   = (const float*)d_in[23];
  const float* a2_bo   = (const float*)d_in[24];

  const size_t MB = 1048576;
  char* ws = (char*)d_ws;
  unsigned short* wqkv1T = (unsigned short*)(ws);
  unsigned short* wo1T   = (unsigned short*)(ws + 6291456);
  unsigned short* wm1aT  = (unsigned short*)(ws + 8388608);
  unsigned short* wm1bT  = (unsigned short*)(ws + 16777216);
  unsigned short* wqkv2T = (unsigned short*)(ws + 25165824);
  unsigned short* wo2T   = (unsigned short*)(ws + 31457280);
  unsigned short* wm2aT  = (unsigned short*)(ws + 33554432);
  unsigned short* wm2bT  = (unsigned short*)(ws + 41943040);
  float*          F2     = (float*)(ws + 48 * MB);
  unsigned short* X      = (unsigned short*)(ws + 112 * MB);
  char*           S      = ws + 144 * MB;
  float*          F1     = (float*)d_out;   // fp32 residual stream (inp1/out1)

  const size_t avail = ws_size > 144 * MB ? ws_size - 144 * MB : 0;
  const int NB = (avail >= 128 * MB) ? 4 : (avail >= 64 * MB) ? 2 : 1;
  const int MC = NB * 4096;                            // rows per chunk
  const int MT = MC / 128;                             // M-tiles per chunk
  unsigned short* Sq = (unsigned short*)S;             // qkv chunk (NB*24MB)
  unsigned short* Sa = (unsigned short*)(S + (size_t)MC * 3072 * 2);  // attn out
  unsigned short* Sm = (unsigned short*)S;             // mlp mid chunk (NB*32MB)

  const dim3 tb(32, 8);
  wconv<<<dim3(96, 32), tb, 0, stream>>>(a1_wqkv, wqkv1T, 1024, 3072);
  wconv<<<dim3(32, 32), tb, 0, stream>>>(a1_wo, wo1T, 1024, 1024);
  wconv<<<dim3(128, 32), tb, 0, stream>>>(mlp1a_w, wm1aT, 1024, 4096);
  wconv<<<dim3(32, 128), tb, 0, stream>>>(mlp1b_w, wm1bT, 4096, 1024);
  wconv<<<dim3(96, 32), tb, 0, stream>>>(a2_wqkv, wqkv2T, 1024, 3072);
  wconv<<<dim3(32, 32), tb, 0, stream>>>(a2_wo, wo2T, 1024, 1024);
  wconv<<<dim3(128, 32), tb, 0, stream>>>(mlp2a_w, wm2aT, 1024, 4096);
  wconv<<<dim3(32, 128), tb, 0, stream>>>(mlp2b_w, wm2bT, 4096, 1024);

  // ---- layer 1: W-MSA ----
  ln_fused<<<16384, 256, 0, stream>>>(x, ln1g, ln1b, F1, X);              // inp1
  for (int b = 0; b < 4; b += NB) {
    const size_t r0 = (size_t)b * 4096;
    gemm_ring<0><<<MT * 12, 512, 0, stream>>>(X + r0 * 1024, wqkv1T,
        a1_bqkv, nullptr, Sq, MC, 3072, 1024);
    attn_win<0><<<NB * 256, 256, 0, stream>>>(Sq, Sa);
    gemm_ring<1><<<MT * 4, 512, 0, stream>>>(Sa, wo1T, a1_bo,
        F1 + r0 * 1024, F2 + r0 * 1024, MC, 1024, 1024);                  // w
  }
  // ---- layer 1: MLP ----
  ln_fused<<<16384, 256, 0, stream>>>(F2, ln2g, ln2b, nullptr, X);
  for (int c = 0; c < 4; c += NB) {
    const size_t r0 = (size_t)c * 4096;
    gemm_ring<0><<<MT * 16, 512, 0, stream>>>(X + r0 * 1024, wm1aT,
        mlp1a_b, nullptr, Sm, MC, 4096, 1024);
    gemm_ring<1><<<MT * 4, 512, 0, stream>>>(Sm, wm1bT, mlp1b_b,
        F2 + r0 * 1024, F1 + r0 * 1024, MC, 1024, 4096);                  // out1
  }

  // ---- layer 2: SW-MSA ----
  ln_fused<<<16384, 256, 0, stream>>>(F1, ln3g, ln3b, nullptr, X);        // inp2
  for (int b = 0; b < 4; b += NB) {
    const size_t r0 = (size_t)b * 4096;
    gemm_ring<0><<<MT * 12, 512, 0, stream>>>(X + r0 * 1024, wqkv2T,
        a2_bqkv, nullptr, Sq, MC, 3072, 1024);
    attn_win<1><<<NB * 256, 256, 0, stream>>>(Sq, Sa);
    gemm_ring<1><<<MT * 4, 512, 0, stream>>>(Sa, wo2T, a2_bo,
        F1 + r0 * 1024, F2 + r0 * 1024, MC, 1024, 1024);                  // sw
  }
  // ---- layer 2: MLP ----
  ln_fused<<<16384, 256, 0, stream>>>(F2, ln4g, ln4b, nullptr, X);
  for (int c = 0; c < 4; c += NB) {
    const size_t r0 = (size_t)c * 4096;
    gemm_ring<0><<<MT * 16, 512, 0, stream>>>(X + r0 * 1024, wm2aT,
        mlp2a_b, nullptr, Sm, MC, 4096, 1024);
    gemm_ring<1><<<MT * 4, 512, 0, stream>>>(Sm, wm2bT, mlp2b_b,
        F2 + r0 * 1024, F1 + r0 * 1024, MC, 1024, 4096);                  // out2
  }
}